// Round 1
// baseline (368.436 us; speedup 1.0000x reference)
//
#include <hip/hip_runtime.h>

// Problem constants: mask_pred (32,16,256,256) f32, pos_gt (32,16,4) int.
constexpr int Wd  = 256;
constexpr int Hd  = 256;
constexpr int BRn = 512;                         // 32*16 images
constexpr long long NTOT = (long long)BRn * Hd * Wd;   // 33,554,432
constexpr int F4_PER_IMG   = Hd * Wd / 4;        // 16384 float4 per image
constexpr int CHUNKS       = 8;                  // blocks per image
constexpr int F4_PER_CHUNK = F4_PER_IMG / CHUNKS;// 2048
constexpr int TPB          = 256;
constexpr int ITERS        = F4_PER_CHUNK / TPB; // 8 float4 per thread

__global__ __launch_bounds__(TPB)
void crop_ce(const float* __restrict__ mp,
             const int* __restrict__ pg,
             float* __restrict__ out,
             double* __restrict__ wsum,
             unsigned int* __restrict__ wcnt,
             unsigned int nblocks) {
    const int img   = blockIdx.x;    // which (b,r) image
    const int chunk = blockIdx.y;    // which 1/8 of the image
    const float4* b4 = (const float4*)(mp + (size_t)img * (Hd * Wd));
    const int y0 = pg[img * 4 + 0];
    const int x0 = pg[img * 4 + 1];
    const int y1 = pg[img * 4 + 2];
    const int x1 = pg[img * 4 + 3];

    float acc = 0.f;
#pragma unroll
    for (int j = 0; j < ITERS; ++j) {
        const int i4 = chunk * F4_PER_CHUNK + j * TPB + (int)threadIdx.x;
        const float4 v = b4[i4];                  // coalesced 16B/lane
        const int idx = i4 * 4;
        const int row = idx >> 8;                 // W = 256
        const int col = idx & 255;
        const bool rin = (row >= y0) & (row <= y1);
        // inside box -> log(p); outside -> log(1-p). One transcendental/elem.
        const float a0 = (rin & (col     >= x0) & (col     <= x1)) ? v.x : 1.f - v.x;
        const float a1 = (rin & (col + 1 >= x0) & (col + 1 <= x1)) ? v.y : 1.f - v.y;
        const float a2 = (rin & (col + 2 >= x0) & (col + 2 <= x1)) ? v.z : 1.f - v.z;
        const float a3 = (rin & (col + 3 >= x0) & (col + 3 <= x1)) ? v.w : 1.f - v.w;
        acc += __logf(a0) + __logf(a1) + __logf(a2) + __logf(a3);
    }

    // wave-64 shuffle reduction
    for (int off = 32; off; off >>= 1) acc += __shfl_down(acc, off);
    __shared__ float wpart[TPB / 64];
    const int lane = threadIdx.x & 63;
    const int wid  = threadIdx.x >> 6;
    if (lane == 0) wpart[wid] = acc;
    __syncthreads();

    if (threadIdx.x == 0) {
        float bs = 0.f;
        for (int k = 0; k < TPB / 64; ++k) bs += wpart[k];
        atomicAdd(wsum, (double)bs);             // device-scope
        __threadfence();
        const unsigned int t = atomicAdd(wcnt, 1u);
        if (t == nblocks - 1) {
            // last block: every block's sum-add happened-before its ticket-add
            const double total = atomicAdd(wsum, 0.0);  // coherent read
            out[0] = (float)(-total / (double)NTOT);
        }
    }
}

extern "C" void kernel_launch(void* const* d_in, const int* in_sizes, int n_in,
                              void* d_out, int out_size, void* d_ws, size_t ws_size,
                              hipStream_t stream) {
    const float* mp = (const float*)d_in[0];
    const int*   pg = (const int*)d_in[1];
    float* out = (float*)d_out;
    double*       wsum = (double*)d_ws;
    unsigned int* wcnt = (unsigned int*)((char*)d_ws + 8);

    // d_ws is re-poisoned to 0xAA before every timed launch -> zero it in-stream
    hipMemsetAsync(d_ws, 0, 16, stream);

    dim3 grid(BRn, CHUNKS);
    crop_ce<<<grid, TPB, 0, stream>>>(mp, pg, out, wsum, wcnt,
                                      (unsigned int)(BRn * CHUNKS));
}

// Round 2
// 190.562 us; speedup vs baseline: 1.9334x; 1.9334x over previous
//
#include <hip/hip_runtime.h>

// Problem constants: mask_pred (32,16,256,256) f32, pos_gt (32,16,4) int.
constexpr int Wd  = 256;
constexpr int Hd  = 256;
constexpr int BRn = 512;                         // 32*16 images
constexpr long long NTOT = (long long)BRn * Hd * Wd;   // 33,554,432
constexpr int F4_PER_IMG   = Hd * Wd / 4;        // 16384 float4 per image
constexpr int CHUNKS       = 8;                  // blocks per image
constexpr int F4_PER_CHUNK = F4_PER_IMG / CHUNKS;// 2048
constexpr int TPB          = 256;
constexpr int ITERS        = F4_PER_CHUNK / TPB; // 8 float4 per thread
constexpr int NBLOCKS      = BRn * CHUNKS;       // 4096 partials

__global__ __launch_bounds__(TPB)
void crop_ce_partial(const float* __restrict__ mp,
                     const int* __restrict__ pg,
                     float* __restrict__ partials) {
    const int img   = blockIdx.x;    // which (b,r) image
    const int chunk = blockIdx.y;    // which 1/8 of the image
    const float4* b4 = (const float4*)(mp + (size_t)img * (Hd * Wd));
    const int y0 = pg[img * 4 + 0];
    const int x0 = pg[img * 4 + 1];
    const int y1 = pg[img * 4 + 2];
    const int x1 = pg[img * 4 + 3];

    float acc = 0.f;
#pragma unroll
    for (int j = 0; j < ITERS; ++j) {
        const int i4 = chunk * F4_PER_CHUNK + j * TPB + (int)threadIdx.x;
        const float4 v = b4[i4];                  // coalesced 16B/lane
        const int idx = i4 * 4;
        const int row = idx >> 8;                 // W = 256
        const int col = idx & 255;
        const bool rin = (row >= y0) & (row <= y1);
        // inside box -> log(p); outside -> log(1-p). One transcendental/elem.
        const float a0 = (rin & (col     >= x0) & (col     <= x1)) ? v.x : 1.f - v.x;
        const float a1 = (rin & (col + 1 >= x0) & (col + 1 <= x1)) ? v.y : 1.f - v.y;
        const float a2 = (rin & (col + 2 >= x0) & (col + 2 <= x1)) ? v.z : 1.f - v.z;
        const float a3 = (rin & (col + 3 >= x0) & (col + 3 <= x1)) ? v.w : 1.f - v.w;
        acc += __logf(a0) + __logf(a1) + __logf(a2) + __logf(a3);
    }

    // wave-64 shuffle reduction
    for (int off = 32; off; off >>= 1) acc += __shfl_down(acc, off);
    __shared__ float wpart[TPB / 64];
    const int lane = threadIdx.x & 63;
    const int wid  = threadIdx.x >> 6;
    if (lane == 0) wpart[wid] = acc;
    __syncthreads();

    if (threadIdx.x == 0) {
        float bs = 0.f;
        for (int k = 0; k < TPB / 64; ++k) bs += wpart[k];
        // plain store — no contention, no pre-zero required (all slots written)
        partials[blockIdx.y * BRn + blockIdx.x] = bs;
    }
}

__global__ __launch_bounds__(TPB)
void crop_ce_final(const float* __restrict__ partials,
                   float* __restrict__ out) {
    // single block: reduce NBLOCKS floats in double
    double acc = 0.0;
#pragma unroll
    for (int j = 0; j < NBLOCKS / TPB; ++j)
        acc += (double)partials[j * TPB + (int)threadIdx.x];

    for (int off = 32; off; off >>= 1) {
        acc += __shfl_down(acc, off);
    }
    __shared__ double wpart[TPB / 64];
    const int lane = threadIdx.x & 63;
    const int wid  = threadIdx.x >> 6;
    if (lane == 0) wpart[wid] = acc;
    __syncthreads();

    if (threadIdx.x == 0) {
        double total = 0.0;
        for (int k = 0; k < TPB / 64; ++k) total += wpart[k];
        out[0] = (float)(-total / (double)NTOT);
    }
}

extern "C" void kernel_launch(void* const* d_in, const int* in_sizes, int n_in,
                              void* d_out, int out_size, void* d_ws, size_t ws_size,
                              hipStream_t stream) {
    const float* mp = (const float*)d_in[0];
    const int*   pg = (const int*)d_in[1];
    float* out      = (float*)d_out;
    float* partials = (float*)d_ws;   // NBLOCKS floats, fully overwritten each launch

    dim3 grid(BRn, CHUNKS);
    crop_ce_partial<<<grid, TPB, 0, stream>>>(mp, pg, partials);
    crop_ce_final<<<1, TPB, 0, stream>>>(partials, out);
}

// Round 3
// 190.151 us; speedup vs baseline: 1.9376x; 1.0022x over previous
//
#include <hip/hip_runtime.h>

// Problem constants: mask_pred (32,16,256,256) f32, pos_gt (32,16,4) int.
constexpr int Wd  = 256;
constexpr int Hd  = 256;
constexpr int BRn = 512;                         // 32*16 images
constexpr long long NTOT = (long long)BRn * Hd * Wd;   // 33,554,432
constexpr int F4_PER_IMG   = Hd * Wd / 4;        // 16384 float4 per image
constexpr int CHUNKS       = 8;                  // blocks per image
constexpr int F4_PER_CHUNK = F4_PER_IMG / CHUNKS;// 2048
constexpr int TPB          = 256;
constexpr int ITERS        = F4_PER_CHUNK / TPB; // 8 float4 per thread
constexpr int NBLOCKS      = BRn * CHUNKS;       // 4096 partials

__global__ __launch_bounds__(TPB)
void crop_ce_partial(const float* __restrict__ mp,
                     const int* __restrict__ pg,
                     float* __restrict__ partials) {
    const int img   = blockIdx.x;    // which (b,r) image
    const int chunk = blockIdx.y;    // which 1/8 of the image
    const float4* b4 = (const float4*)(mp + (size_t)img * (Hd * Wd));
    const int y0 = pg[img * 4 + 0];
    const int x0 = pg[img * 4 + 1];
    const int y1 = pg[img * 4 + 2];
    const int x1 = pg[img * 4 + 3];

    // Phase 1: issue ALL loads back-to-back (8 float4 = 32 VGPRs in flight)
    // so the wave has 8 outstanding vmem ops instead of 1 — latency-hiding
    // via MLP, not just TLP. (R2's VGPR_Count=12 showed the compiler was
    // serializing load->wait->compute per iteration.)
    float4 v[ITERS];
#pragma unroll
    for (int j = 0; j < ITERS; ++j) {
        const int i4 = chunk * F4_PER_CHUNK + j * TPB + (int)threadIdx.x;
        v[j] = b4[i4];
    }

    // Phase 2: compute. inside box -> log(p); outside -> log(1-p).
    float acc = 0.f;
#pragma unroll
    for (int j = 0; j < ITERS; ++j) {
        const int i4 = chunk * F4_PER_CHUNK + j * TPB + (int)threadIdx.x;
        const int idx = i4 * 4;
        const int row = idx >> 8;                 // W = 256
        const int col = idx & 255;
        const bool rin = (row >= y0) & (row <= y1);
        const float a0 = (rin & (col     >= x0) & (col     <= x1)) ? v[j].x : 1.f - v[j].x;
        const float a1 = (rin & (col + 1 >= x0) & (col + 1 <= x1)) ? v[j].y : 1.f - v[j].y;
        const float a2 = (rin & (col + 2 >= x0) & (col + 2 <= x1)) ? v[j].z : 1.f - v[j].z;
        const float a3 = (rin & (col + 3 >= x0) & (col + 3 <= x1)) ? v[j].w : 1.f - v[j].w;
        acc += __logf(a0) + __logf(a1) + __logf(a2) + __logf(a3);
    }

    // wave-64 shuffle reduction
    for (int off = 32; off; off >>= 1) acc += __shfl_down(acc, off);
    __shared__ float wpart[TPB / 64];
    const int lane = threadIdx.x & 63;
    const int wid  = threadIdx.x >> 6;
    if (lane == 0) wpart[wid] = acc;
    __syncthreads();

    if (threadIdx.x == 0) {
        float bs = 0.f;
        for (int k = 0; k < TPB / 64; ++k) bs += wpart[k];
        // plain store — no contention, no pre-zero required (all slots written)
        partials[blockIdx.y * BRn + blockIdx.x] = bs;
    }
}

__global__ __launch_bounds__(TPB)
void crop_ce_final(const float* __restrict__ partials,
                   float* __restrict__ out) {
    // single block: reduce NBLOCKS floats in double
    double acc = 0.0;
#pragma unroll
    for (int j = 0; j < NBLOCKS / TPB; ++j)
        acc += (double)partials[j * TPB + (int)threadIdx.x];

    for (int off = 32; off; off >>= 1) {
        acc += __shfl_down(acc, off);
    }
    __shared__ double wpart[TPB / 64];
    const int lane = threadIdx.x & 63;
    const int wid  = threadIdx.x >> 6;
    if (lane == 0) wpart[wid] = acc;
    __syncthreads();

    if (threadIdx.x == 0) {
        double total = 0.0;
        for (int k = 0; k < TPB / 64; ++k) total += wpart[k];
        out[0] = (float)(-total / (double)NTOT);
    }
}

extern "C" void kernel_launch(void* const* d_in, const int* in_sizes, int n_in,
                              void* d_out, int out_size, void* d_ws, size_t ws_size,
                              hipStream_t stream) {
    const float* mp = (const float*)d_in[0];
    const int*   pg = (const int*)d_in[1];
    float* out      = (float*)d_out;
    float* partials = (float*)d_ws;   // NBLOCKS floats, fully overwritten each launch

    dim3 grid(BRn, CHUNKS);
    crop_ce_partial<<<grid, TPB, 0, stream>>>(mp, pg, partials);
    crop_ce_final<<<1, TPB, 0, stream>>>(partials, out);
}